// Round 1
// baseline (4937.217 us; speedup 1.0000x reference)
//
#include <hip/hip_runtime.h>
#include <math.h>

#define B_ 8
#define N_ 2048
#define H_ 128
#define BN_ (B_ * N_)

// ws layout: A [BN][H] f32 | C [BN][H] f32 | Z [B][N][N] f32
// need = 2*8MB + 128MB = 150,994,944 bytes

__device__ __forceinline__ float elu1(float x) {
    return x > 0.f ? x : (__expf(x) - 1.f);
}

// ---------------- K1: A = emb@W1[:H] ; C = emb@W1[H:] + b1 ----------------
__global__ __launch_bounds__(H_) void k_ac(const float* __restrict__ emb,
                                           const float* __restrict__ W1,
                                           const float* __restrict__ b1,
                                           float* __restrict__ A,
                                           float* __restrict__ C) {
    __shared__ float e[H_];
    const int i = blockIdx.x;
    const int k = threadIdx.x;
    e[k] = emb[(size_t)i * H_ + k];
    __syncthreads();
    float a = 0.f, c = 0.f;
#pragma unroll 8
    for (int h = 0; h < H_; ++h) {
        const float ev = e[h];
        a = fmaf(ev, W1[h * H_ + k], a);
        c = fmaf(ev, W1[(H_ + h) * H_ + k], c);
    }
    A[(size_t)i * H_ + k] = a;
    C[(size_t)i * H_ + k] = c + b1[k];
}

// ---------------- K2: Z[g][i][j] = w2 . elu(A_i + C_j) + b2 ----------------
// 16-lane h-split groups: lane = 4 groups (i) x 16 h-parts of 8 elems.
// A-row and w2 slice live in registers; C_j loads are broadcast-coalesced.
__global__ __launch_bounds__(256) void k_z(const float* __restrict__ A,
                                           const float* __restrict__ Cc,
                                           const float* __restrict__ w2,
                                           const float* __restrict__ b2p,
                                           float* __restrict__ Z) {
    const int lane = threadIdx.x & 63;
    const int wave = threadIdx.x >> 6;          // 0..3
    const int g = blockIdx.x >> 7;              // 128 blocks per graph
    const int ibase = (blockIdx.x & 127) * 16 + wave * 4;
    const int i = ibase + (lane & 3);           // this group's row
    const int he = (lane >> 2) * 8;             // h-slice start (0..120)
    const float b2v = *b2p;

    const float* Arow = A + ((size_t)g * N_ + i) * H_ + he;
    const float4 a0 = *(const float4*)(Arow);
    const float4 a1 = *(const float4*)(Arow + 4);
    const float4 w0 = *(const float4*)(w2 + he);
    const float4 w1v = *(const float4*)(w2 + he + 4);
    const float* Cg = Cc + (size_t)g * N_ * H_ + he;
    float* Zrow = Z + ((size_t)g * N_ + i) * N_;
    const bool writer = ((lane >> 2) == 0);

    auto zc = [&](int j) -> float {
        const float* Cj = Cg + (size_t)j * H_;
        const float4 c0 = *(const float4*)(Cj);
        const float4 c1 = *(const float4*)(Cj + 4);
        float p = 0.f;
        p = fmaf(w0.x, elu1(a0.x + c0.x), p);
        p = fmaf(w0.y, elu1(a0.y + c0.y), p);
        p = fmaf(w0.z, elu1(a0.z + c0.z), p);
        p = fmaf(w0.w, elu1(a0.w + c0.w), p);
        p = fmaf(w1v.x, elu1(a1.x + c1.x), p);
        p = fmaf(w1v.y, elu1(a1.y + c1.y), p);
        p = fmaf(w1v.z, elu1(a1.z + c1.z), p);
        p = fmaf(w1v.w, elu1(a1.w + c1.w), p);
        p += __shfl_xor(p, 4);
        p += __shfl_xor(p, 8);
        p += __shfl_xor(p, 16);
        p += __shfl_xor(p, 32);
        return p + b2v;
    };

    for (int j = 0; j < N_; j += 4) {
        float4 zb;
        zb.x = zc(j);
        zb.y = zc(j + 1);
        zb.z = zc(j + 2);
        zb.w = zc(j + 3);
        if (writer) *(float4*)(Zrow + j) = zb;
    }
}

// ---------------- K3: sequential greedy chain, one wave per graph ----------
__global__ __launch_bounds__(64) void k_path(const float* __restrict__ emb,
                                             const float* __restrict__ Z,
                                             float* __restrict__ out) {
    const int g = blockIdx.x;
    const int lane = threadIdx.x;  // 0..63
    __shared__ unsigned char vis[N_];
    for (int j = lane; j < N_; j += 64) vis[j] = 0;

    // root = argmax_j emb[g][j][0], first-max tie-break
    float bv = -INFINITY;
    int bi = 0x7fffffff;
    for (int j = lane; j < N_; j += 64) {
        const float v = emb[((size_t)g * N_ + j) * H_];
        if (v > bv) { bv = v; bi = j; }  // ascending j per lane keeps first max
    }
#pragma unroll
    for (int off = 1; off < 64; off <<= 1) {
        const float ov = __shfl_xor(bv, off);
        const int oi = __shfl_xor(bi, off);
        if (ov > bv || (ov == bv && oi < bi)) { bv = ov; bi = oi; }
    }
    int cur = bi;
    float* pathOut = out + (size_t)g * N_;
    float* scoreOut = out + (size_t)BN_ + (size_t)g * N_;
    if (lane == 0) {
        vis[cur] = 1;
        pathOut[0] = (float)cur;
        scoreOut[0] = 1.0f;
    }
    __syncthreads();

    int t = 1;
    for (; t < N_; ++t) {
        const float* Zrow = Z + ((size_t)g * N_ + cur) * N_;
        float bestv = -INFINITY;
        int besti = 0x7fffffff;
#pragma unroll
        for (int k = 0; k < N_ / 256; ++k) {
            const int j = k * 256 + lane * 4;
            const float4 z4 = *(const float4*)(Zrow + j);
            const uchar4 v4 = *(const uchar4*)(vis + j);
            if (!v4.x && z4.x > bestv) { bestv = z4.x; besti = j; }
            if (!v4.y && z4.y > bestv) { bestv = z4.y; besti = j + 1; }
            if (!v4.z && z4.z > bestv) { bestv = z4.z; besti = j + 2; }
            if (!v4.w && z4.w > bestv) { bestv = z4.w; besti = j + 3; }
        }
#pragma unroll
        for (int off = 1; off < 64; off <<= 1) {
            const float ov = __shfl_xor(bestv, off);
            const int oi = __shfl_xor(besti, off);
            if (ov > bestv || (ov == bestv && oi < besti)) { bestv = ov; besti = oi; }
        }
        const float s = 1.f / (1.f + expf(-bestv));
        if (!((double)s > 0.3)) break;  // matches sigmoid(z) > 0.3 semantics
        cur = besti;
        if (lane == 0) {
            vis[cur] = 1;
            pathOut[t] = (float)cur;
            scoreOut[t] = s;
        }
        __syncthreads();
    }
    for (int tt = t + lane; tt < N_; tt += 64) {
        pathOut[tt] = -1.f;
        scoreOut[tt] = 0.f;
    }
}

// ---------------- Fallback: on-the-fly scoring (ws too small for Z) --------
__device__ __forceinline__ void blockArgmax(float& bv, int& bi, float* rv, int* ri,
                                            int lane, int wid, int nw) {
#pragma unroll
    for (int off = 1; off < 64; off <<= 1) {
        const float ov = __shfl_xor(bv, off);
        const int oi = __shfl_xor(bi, off);
        if (ov > bv || (ov == bv && oi < bi)) { bv = ov; bi = oi; }
    }
    if (lane == 0) { rv[wid] = bv; ri[wid] = bi; }
    __syncthreads();
    if (wid == 0) {
        float v = (lane < nw) ? rv[lane] : -INFINITY;
        int ix = (lane < nw) ? ri[lane] : 0x7fffffff;
#pragma unroll
        for (int off = 1; off < 16; off <<= 1) {
            const float ov = __shfl_xor(v, off);
            const int oi = __shfl_xor(ix, off);
            if (ov > v || (ov == v && oi < ix)) { v = ov; ix = oi; }
        }
        if (lane == 0) { rv[0] = v; ri[0] = ix; }
    }
    __syncthreads();
    bv = rv[0];
    bi = ri[0];
}

__global__ __launch_bounds__(1024) void k_path_fly(const float* __restrict__ emb,
                                                   const float* __restrict__ A,
                                                   const float* __restrict__ Cc,
                                                   const float* __restrict__ w2g,
                                                   const float* __restrict__ b2p,
                                                   float* __restrict__ out) {
    const int g = blockIdx.x;
    const int tid = threadIdx.x;
    const int lane = tid & 63, wid = tid >> 6;
    __shared__ float acur[H_], w2s[H_];
    __shared__ unsigned char vis[N_];
    __shared__ float rv[16];
    __shared__ int ri[16];
    const float b2v = *b2p;
    if (tid < H_) w2s[tid] = w2g[tid];
    for (int j = tid; j < N_; j += 1024) vis[j] = 0;

    float bv = -INFINITY;
    int bi = 0x7fffffff;
    for (int j = tid; j < N_; j += 1024) {
        const float v = emb[((size_t)g * N_ + j) * H_];
        if (v > bv) { bv = v; bi = j; }
    }
    __syncthreads();
    blockArgmax(bv, bi, rv, ri, lane, wid, 16);
    int cur = bi;
    float* pathOut = out + (size_t)g * N_;
    float* scoreOut = out + (size_t)BN_ + (size_t)g * N_;
    if (tid == 0) {
        vis[cur] = 1;
        pathOut[0] = (float)cur;
        scoreOut[0] = 1.0f;
    }
    __syncthreads();

    int t = 1;
    for (; t < N_; ++t) {
        if (tid < H_) acur[tid] = A[((size_t)g * N_ + cur) * H_ + tid];
        __syncthreads();
        float mbv = -INFINITY;
        int mbi = 0x7fffffff;
#pragma unroll
        for (int q = 0; q < 2; ++q) {
            const int j = tid + q * 1024;
            const float* Cj = Cc + ((size_t)g * N_ + j) * H_;
            float p = 0.f;
            for (int h = 0; h < H_; h += 4) {
                const float4 c = *(const float4*)(Cj + h);
                p = fmaf(w2s[h + 0], elu1(acur[h + 0] + c.x), p);
                p = fmaf(w2s[h + 1], elu1(acur[h + 1] + c.y), p);
                p = fmaf(w2s[h + 2], elu1(acur[h + 2] + c.z), p);
                p = fmaf(w2s[h + 3], elu1(acur[h + 3] + c.w), p);
            }
            const float z = p + b2v;
            if (!vis[j] && (z > mbv || (z == mbv && j < mbi))) { mbv = z; mbi = j; }
        }
        __syncthreads();
        blockArgmax(mbv, mbi, rv, ri, lane, wid, 16);
        const float s = 1.f / (1.f + expf(-mbv));
        if (!((double)s > 0.3)) break;
        cur = mbi;
        if (tid == 0) {
            vis[cur] = 1;
            pathOut[t] = (float)cur;
            scoreOut[t] = s;
        }
        __syncthreads();
    }
    for (int tt = t + tid; tt < N_; tt += 1024) {
        pathOut[tt] = -1.f;
        scoreOut[tt] = 0.f;
    }
}

extern "C" void kernel_launch(void* const* d_in, const int* in_sizes, int n_in,
                              void* d_out, int out_size, void* d_ws, size_t ws_size,
                              hipStream_t stream) {
    (void)in_sizes; (void)n_in; (void)out_size;
    const float* emb = (const float*)d_in[0];
    // d_in[1] = batch (int64) — contiguous equal-sized graphs, unused
    const float* W1 = (const float*)d_in[2];
    const float* b1 = (const float*)d_in[3];
    const float* w2 = (const float*)d_in[4];
    const float* b2 = (const float*)d_in[5];
    float* out = (float*)d_out;

    float* A = (float*)d_ws;
    float* C = A + (size_t)BN_ * H_;
    float* Z = C + (size_t)BN_ * H_;
    const size_t need = ((size_t)BN_ * H_ * 2 + (size_t)B_ * N_ * N_) * sizeof(float);

    hipLaunchKernelGGL(k_ac, dim3(BN_), dim3(H_), 0, stream, emb, W1, b1, A, C);
    if (ws_size >= need) {
        hipLaunchKernelGGL(k_z, dim3(1024), dim3(256), 0, stream, A, C, w2, b2, Z);
        hipLaunchKernelGGL(k_path, dim3(B_), dim3(64), 0, stream, emb, Z, out);
    } else {
        hipLaunchKernelGGL(k_path_fly, dim3(B_), dim3(1024), 0, stream,
                           emb, A, C, w2, b2, out);
    }
}